// Round 2
// baseline (397.606 us; speedup 1.0000x reference)
//
#include <hip/hip_runtime.h>
#include <hip/hip_bf16.h>
#include <stdint.h>

// Problem constants (PointerGenNetwork): T=64 B=32 S=400 V=32000 D=1536
#define T_DIM 64
#define B_DIM 32
#define S_DIM 400
#define V_DIM 32000
#define D_DIM 1536
#define M_DIM (T_DIM * B_DIM)   // 2048

typedef __attribute__((ext_vector_type(8))) short bf16x8;
typedef __attribute__((ext_vector_type(4))) float f32x4;

#define MEMFENCE asm volatile("" ::: "memory")
#define BARRIER() do { MEMFENCE; __builtin_amdgcn_s_barrier(); MEMFENCE; } while (0)

// ---------------- helpers ----------------

static __device__ __forceinline__ unsigned short f2bf(float x) {
    union { float f; uint32_t u; } v; v.f = x;
    uint32_t r = (v.u + 0x7FFFu + ((v.u >> 16) & 1u)) >> 16;   // RNE f32->bf16
    return (unsigned short)r;
}

static __device__ __forceinline__ void gload_lds16(const void* g, void* l) {
    __builtin_amdgcn_global_load_lds(
        (const __attribute__((address_space(1))) uint32_t*)g,
        (__attribute__((address_space(3))) uint32_t*)l,
        16, 0, 0);
}

// ---------------- pre-pass: h fp32 -> bf16 ----------------

__global__ void convert_h(const float* __restrict__ h, unsigned short* __restrict__ hb) {
    const size_t n4 = (size_t)M_DIM * D_DIM / 4;
    for (size_t i = (size_t)blockIdx.x * blockDim.x + threadIdx.x; i < n4;
         i += (size_t)gridDim.x * blockDim.x) {
        const float4 v = ((const float4*)h)[i];
        ushort4 o;
        o.x = f2bf(v.x); o.y = f2bf(v.y); o.z = f2bf(v.z); o.w = f2bf(v.w);
        ((ushort4*)hb)[i] = o;
    }
}

// ---------------- pre-pass: W (K x V fp32) -> Wt (V x K bf16) ----------------

__global__ __launch_bounds__(256)
void convT_W(const float* __restrict__ W, unsigned short* __restrict__ Wt) {
    __shared__ unsigned short lds[64 * 66];   // 64x64 tile, padded stride 66
    const int k0 = blockIdx.x * 64;           // 1536/64 = 24
    const int v0 = blockIdx.y * 64;           // 32000/64 = 500
    const int tid = threadIdx.x;
    const int rr = tid >> 4;                  // 0..15
    const int cc = (tid & 15) * 4;            // 0..60

    #pragma unroll
    for (int p = 0; p < 4; ++p) {
        const int r = p * 16 + rr;
        const float4 v = *(const float4*)&W[(size_t)(k0 + r) * V_DIM + v0 + cc];
        unsigned short* q = &lds[r * 66 + cc];
        q[0] = f2bf(v.x); q[1] = f2bf(v.y); q[2] = f2bf(v.z); q[3] = f2bf(v.w);
    }
    __syncthreads();
    #pragma unroll
    for (int p = 0; p < 4; ++p) {
        const int n = p * 16 + rr;
        ushort4 o;
        o.x = lds[(cc + 0) * 66 + n];
        o.y = lds[(cc + 1) * 66 + n];
        o.z = lds[(cc + 2) * 66 + n];
        o.w = lds[(cc + 3) * 66 + n];
        *(ushort4*)&Wt[(size_t)(v0 + n) * D_DIM + k0 + cc] = o;
    }
}

// ---------------- main GEMM: 256x256 tile, 8-wave, multi-phase counted-vmcnt ----------------
// A: M x K bf16 row-major. Bt: N x K bf16 row-major.
// Ring of 4 LDS K-tile buffers (BK=32), 2 phases per K-tile (16 MFMA each),
// raw s_barrier (no vmcnt drain), counted vmcnt(8) at tile boundaries,
// setprio around MFMA clusters, XOR-swizzled LDS (pre-swizzled global src,
// linear global_load_lds dest, swizzled ds_read).

#define GBM 256
#define GBN 256
#define GBK 32
#define GNKT (D_DIM / GBK)   // 48

__global__ __launch_bounds__(512, 2)
void gemm_mfma256(const unsigned short* __restrict__ A,
                  const unsigned short* __restrict__ Bt,
                  const float* __restrict__ bias,
                  const float* __restrict__ p_gen,
                  float* __restrict__ out) {
    __shared__ unsigned short ldsA[4][GBM * GBK];   // 4 x 16 KB
    __shared__ unsigned short ldsB[4][GBN * GBK];   // 4 x 16 KB  (128 KB total)

    // XCD-aware swizzle: 1000 blocks, 1000 % 8 == 0 -> simple bijective form.
    const int bid = blockIdx.x;
    const int swz = (bid & 7) * 125 + (bid >> 3);
    const int m0 = (swz & 7) * GBM;    // 8 m-tiles (fastest: W-panel L2 reuse per XCD)
    const int n0 = (swz >> 3) * GBN;   // 125 n-tiles

    const int tid = threadIdx.x;
    const int lane = tid & 63;
    const int wid = tid >> 6;
    const int wr = wid >> 2;          // 0..1  -> rows wr*128 + [0,128)
    const int wc = wid & 3;           // 0..3  -> cols wc*64 + [0,64)
    const int rq = lane & 15;
    const int kq = (lane >> 4) * 8;   // ushort k-offset within BK

    // ---- staging addresses: physical LDS offset o = tid*16 + j*8192 (linear dest).
    // logical col-byte = (o&63) ^ (((o>>7)&3)<<4)  [row = o>>6, swz bits from row>>1]
    const char* gA[2]; const char* gB[2]; int ldsOff[2];
    #pragma unroll
    for (int j = 0; j < 2; ++j) {
        const int o = tid * 16 + j * 8192;
        const int row = o >> 6;
        const int lc = (o & 63) ^ (((row >> 1) & 3) << 4);
        gA[j] = (const char*)A + (size_t)(m0 + row) * D_DIM * 2 + lc;
        gB[j] = (const char*)Bt + (size_t)(n0 + row) * D_DIM * 2 + lc;
        ldsOff[j] = o;
    }

    #define STAGE2(kt, j)                                                        \
        do {                                                                     \
            const int _b = (kt) & 3;                                             \
            gload_lds16(gA[j] + (size_t)(kt) * (GBK * 2),                        \
                        (char*)&ldsA[_b][0] + ldsOff[j]);                        \
            gload_lds16(gB[j] + (size_t)(kt) * (GBK * 2),                        \
                        (char*)&ldsB[_b][0] + ldsOff[j]);                        \
        } while (0)

    // ---- fragment read offsets (bytes within one buffer), swizzled
    int aOff0[4], aOff1[4], bOff[4];
    #pragma unroll
    for (int i = 0; i < 4; ++i) {
        int r0 = wr * 128 + i * 16 + rq;
        int r1 = r0 + 64;
        aOff0[i] = r0 * 64 + ((kq * 2) ^ (((r0 >> 1) & 3) << 4));
        aOff1[i] = r1 * 64 + ((kq * 2) ^ (((r1 >> 1) & 3) << 4));
        int rb = wc * 64 + i * 16 + rq;
        bOff[i] = rb * 64 + ((kq * 2) ^ (((rb >> 1) & 3) << 4));
    }

    f32x4 acc[8][4] = {};

    // ---- prologue: stage tiles 0,1,2 (12 loads); wait tile 0 (keep 8 in flight)
    #pragma unroll
    for (int t = 0; t < 3; ++t) { STAGE2(t, 0); STAGE2(t, 1); }
    asm volatile("s_waitcnt vmcnt(8)" ::: "memory");
    BARRIER();

    for (int kt = 0; kt < GNKT; ++kt) {
        const char* As = (const char*)&ldsA[kt & 3][0];
        const char* Bs = (const char*)&ldsB[kt & 3][0];
        bf16x8 a[4], b[4];

        // ===== phase 0: rows wr*128+[0,64) =====
        #pragma unroll
        for (int i = 0; i < 4; ++i) a[i] = *(const bf16x8*)(As + aOff0[i]);
        #pragma unroll
        for (int j = 0; j < 4; ++j) b[j] = *(const bf16x8*)(Bs + bOff[j]);
        if (kt + 3 < GNKT) STAGE2(kt + 3, 0);
        BARRIER();
        __builtin_amdgcn_s_setprio(1);
        #pragma unroll
        for (int mi = 0; mi < 4; ++mi)
            #pragma unroll
            for (int nj = 0; nj < 4; ++nj)
                acc[mi][nj] = __builtin_amdgcn_mfma_f32_16x16x32_bf16(a[mi], b[nj], acc[mi][nj], 0, 0, 0);
        __builtin_amdgcn_s_setprio(0);
        BARRIER();

        // ===== phase 1: rows wr*128+[64,128) (b reused) =====
        #pragma unroll
        for (int i = 0; i < 4; ++i) a[i] = *(const bf16x8*)(As + aOff1[i]);
        if (kt + 3 < GNKT) STAGE2(kt + 3, 1);
        BARRIER();
        __builtin_amdgcn_s_setprio(1);
        #pragma unroll
        for (int mi = 0; mi < 4; ++mi)
            #pragma unroll
            for (int nj = 0; nj < 4; ++nj)
                acc[4 + mi][nj] = __builtin_amdgcn_mfma_f32_16x16x32_bf16(a[mi], b[nj], acc[4 + mi][nj], 0, 0, 0);
        __builtin_amdgcn_s_setprio(0);

        // tile boundary: ensure tile kt+1 resident. Newer-than-(kt+1) staged
        // instructions: tiles kt+2..min(kt+3,47) -> 8 / 4 / 0.
        if (kt < GNKT - 3)       { asm volatile("s_waitcnt vmcnt(8)" ::: "memory"); }
        else if (kt == GNKT - 3) { asm volatile("s_waitcnt vmcnt(4)" ::: "memory"); }
        else if (kt == GNKT - 2) { asm volatile("s_waitcnt vmcnt(0)" ::: "memory"); }
        BARRIER();
    }

    // ---- epilogue: C/D layout col=lane&15, row=(lane>>4)*4+reg
    const int rr4 = (lane >> 4) * 4;
    #pragma unroll
    for (int mi = 0; mi < 8; ++mi) {
        #pragma unroll
        for (int r = 0; r < 4; ++r) {
            const int m = m0 + wr * 128 + mi * 16 + rr4 + r;
            const float pgv = p_gen[m];
            #pragma unroll
            for (int nj = 0; nj < 4; ++nj) {
                const int n = n0 + wc * 64 + nj * 16 + rq;
                out[(size_t)m * V_DIM + n] = pgv * (acc[mi][nj][r] + bias[n]);
            }
        }
    }
    #undef STAGE2
}

// ---------------- scatter: out[t,b,post[s,b]] += (1-pg[t,b]) * att[t,b,s] ----------------

__global__ void scatter_att(const float* __restrict__ att, const float* __restrict__ p_gen,
                            const int* __restrict__ post, float* __restrict__ out) {
    const int tb = blockIdx.x;             // t*B + b
    const int b = tb & (B_DIM - 1);
    const float g = 1.0f - p_gen[tb];
    float* o = out + (size_t)tb * V_DIM;
    const float* a = att + (size_t)tb * S_DIM;
    for (int s = threadIdx.x; s < S_DIM; s += blockDim.x) {
        atomicAdd(&o[post[s * B_DIM + b]], g * a[s]);
    }
}

// ---------------- fallback (ws too small): fp32 vector GEMM ----------------

#define FB_MT 16
__global__ __launch_bounds__(256)
void gemm_naive(const float* __restrict__ h, const float* __restrict__ W,
                const float* __restrict__ bias, const float* __restrict__ pg,
                float* __restrict__ out) {
    const int mb = blockIdx.y;
    const int v = blockIdx.x * 256 + threadIdx.x;
    __shared__ float hs[FB_MT][128];
    float acc[FB_MT] = {};
    for (int k0 = 0; k0 < D_DIM; k0 += 128) {
        for (int i = threadIdx.x; i < FB_MT * 128; i += 256)
            hs[i >> 7][i & 127] = h[(size_t)(mb * FB_MT + (i >> 7)) * D_DIM + k0 + (i & 127)];
        __syncthreads();
        for (int kk = 0; kk < 128; ++kk) {
            const float wv = W[(size_t)(k0 + kk) * V_DIM + v];
            #pragma unroll
            for (int i = 0; i < FB_MT; ++i) acc[i] += hs[i][kk] * wv;
        }
        __syncthreads();
    }
    #pragma unroll
    for (int i = 0; i < FB_MT; ++i) {
        const int m = mb * FB_MT + i;
        out[(size_t)m * V_DIM + v] = pg[m] * (acc[i] + bias[v]);
    }
}

// ---------------- launcher ----------------

extern "C" void kernel_launch(void* const* d_in, const int* in_sizes, int n_in,
                              void* d_out, int out_size, void* d_ws, size_t ws_size,
                              hipStream_t stream) {
    const float* h    = (const float*)d_in[0];   // (T,B,D)
    const float* W    = (const float*)d_in[1];   // (D,V)
    const float* bias = (const float*)d_in[2];   // (V,)
    const float* att  = (const float*)d_in[3];   // (T,B,S)
    const float* pg   = (const float*)d_in[4];   // (T,B,1)
    const int*   post = (const int*)d_in[5];     // (S,B)
    float* out = (float*)d_out;                  // (T,B,V) fp32

    const size_t wt_bytes = (size_t)V_DIM * D_DIM * 2;   // 98,304,000
    const size_t hb_bytes = (size_t)M_DIM * D_DIM * 2;   //  6,291,456

    if (ws_size >= wt_bytes + hb_bytes) {
        unsigned short* Wt = (unsigned short*)d_ws;
        unsigned short* hb = (unsigned short*)((char*)d_ws + wt_bytes);
        convert_h<<<1024, 256, 0, stream>>>(h, hb);
        dim3 tg(D_DIM / 64, V_DIM / 64);   // 24 x 500
        convT_W<<<tg, 256, 0, stream>>>(W, Wt);
        gemm_mfma256<<<(M_DIM / GBM) * (V_DIM / GBN), 512, 0, stream>>>(hb, Wt, bias, pg, out);
    } else {
        dim3 fg(V_DIM / 256, M_DIM / FB_MT);
        gemm_naive<<<fg, 256, 0, stream>>>(h, W, bias, pg, out);
    }

    scatter_att<<<M_DIM, 256, 0, stream>>>(att, pg, post, out);
}

// Round 3
// 387.233 us; speedup vs baseline: 1.0268x; 1.0268x over previous
//
#include <hip/hip_runtime.h>
#include <hip/hip_bf16.h>
#include <stdint.h>

// Problem constants (PointerGenNetwork): T=64 B=32 S=400 V=32000 D=1536
#define T_DIM 64
#define B_DIM 32
#define S_DIM 400
#define V_DIM 32000
#define D_DIM 1536
#define M_DIM (T_DIM * B_DIM)   // 2048

typedef __attribute__((ext_vector_type(8))) short bf16x8;
typedef __attribute__((ext_vector_type(4))) float f32x4;

#define MEMFENCE asm volatile("" ::: "memory")
#define BARRIER() do { MEMFENCE; __builtin_amdgcn_s_barrier(); MEMFENCE; } while (0)

// ---------------- helpers ----------------

static __device__ __forceinline__ unsigned short f2bf(float x) {
    union { float f; uint32_t u; } v; v.f = x;
    uint32_t r = (v.u + 0x7FFFu + ((v.u >> 16) & 1u)) >> 16;   // RNE f32->bf16
    return (unsigned short)r;
}

static __device__ __forceinline__ void gload_lds16(const void* g, void* l) {
    __builtin_amdgcn_global_load_lds(
        (const __attribute__((address_space(1))) uint32_t*)g,
        (__attribute__((address_space(3))) uint32_t*)l,
        16, 0, 0);
}

// ---------------- pre-pass: h fp32 -> bf16 ----------------

__global__ void convert_h(const float* __restrict__ h, unsigned short* __restrict__ hb) {
    const size_t n4 = (size_t)M_DIM * D_DIM / 4;
    for (size_t i = (size_t)blockIdx.x * blockDim.x + threadIdx.x; i < n4;
         i += (size_t)gridDim.x * blockDim.x) {
        const float4 v = ((const float4*)h)[i];
        ushort4 o;
        o.x = f2bf(v.x); o.y = f2bf(v.y); o.z = f2bf(v.z); o.w = f2bf(v.w);
        ((ushort4*)hb)[i] = o;
    }
}

// ---------------- pre-pass: W (K x V fp32) -> Wt (V x K bf16) ----------------

__global__ __launch_bounds__(256)
void convT_W(const float* __restrict__ W, unsigned short* __restrict__ Wt) {
    __shared__ unsigned short lds[64 * 66];   // 64x64 tile, padded stride 66
    const int k0 = blockIdx.x * 64;           // 1536/64 = 24
    const int v0 = blockIdx.y * 64;           // 32000/64 = 500
    const int tid = threadIdx.x;
    const int rr = tid >> 4;                  // 0..15
    const int cc = (tid & 15) * 4;            // 0..60

    #pragma unroll
    for (int p = 0; p < 4; ++p) {
        const int r = p * 16 + rr;
        const float4 v = *(const float4*)&W[(size_t)(k0 + r) * V_DIM + v0 + cc];
        unsigned short* q = &lds[r * 66 + cc];
        q[0] = f2bf(v.x); q[1] = f2bf(v.y); q[2] = f2bf(v.z); q[3] = f2bf(v.w);
    }
    __syncthreads();
    #pragma unroll
    for (int p = 0; p < 4; ++p) {
        const int n = p * 16 + rr;
        ushort4 o;
        o.x = lds[(cc + 0) * 66 + n];
        o.y = lds[(cc + 1) * 66 + n];
        o.z = lds[(cc + 2) * 66 + n];
        o.w = lds[(cc + 3) * 66 + n];
        *(ushort4*)&Wt[(size_t)(v0 + n) * D_DIM + k0 + cc] = o;
    }
}

// ---------------- main GEMM: 256x256 tile, 8-wave, phase-pipelined ----------------
// A: M x K bf16 row-major. Bt: N x K bf16 row-major.
// Ring of 4 LDS K-tile buffers (BK=32), 2 phases per K-tile (16 MFMA each).
// Fragment ds_reads are issued ONE PHASE AHEAD of their MFMA cluster, so the
// MFMA-time lgkm wait is ~0. One raw s_barrier per phase; counted vmcnt(6)
// at tile boundaries placed BEFORE the cross-tile pre-reads. b-fragments in
// named even/odd register sets (K-loop unrolled x2 => static indices).

#define GBM 256
#define GBN 256
#define GBK 32
#define GNKT (D_DIM / GBK)   // 48

__global__ __launch_bounds__(512, 2)
void gemm_mfma256(const unsigned short* __restrict__ A,
                  const unsigned short* __restrict__ Bt,
                  const float* __restrict__ bias,
                  const float* __restrict__ p_gen,
                  float* __restrict__ out) {
    __shared__ unsigned short ldsA[4][GBM * GBK];   // 4 x 16 KB
    __shared__ unsigned short ldsB[4][GBN * GBK];   // 4 x 16 KB  (128 KB total)

    // XCD-aware swizzle: 1000 blocks, 1000 % 8 == 0 -> simple bijective form.
    const int bid = blockIdx.x;
    const int swz = (bid & 7) * 125 + (bid >> 3);
    const int m0 = (swz & 7) * GBM;    // 8 m-tiles (fastest: W-panel L2 reuse per XCD)
    const int n0 = (swz >> 3) * GBN;   // 125 n-tiles

    const int tid = threadIdx.x;
    const int lane = tid & 63;
    const int wid = tid >> 6;
    const int wr = wid >> 2;          // 0..1  -> rows wr*128 + [0,128)
    const int wc = wid & 3;           // 0..3  -> cols wc*64 + [0,64)
    const int rq = lane & 15;
    const int kq = (lane >> 4) * 8;   // ushort k-offset within BK

    // ---- staging addresses: physical LDS offset o = tid*16 + j*8192 (linear dest).
    const char* gA[2]; const char* gB[2]; int ldsOff[2];
    #pragma unroll
    for (int j = 0; j < 2; ++j) {
        const int o = tid * 16 + j * 8192;
        const int row = o >> 6;
        const int lc = (o & 63) ^ (((row >> 1) & 3) << 4);   // pre-swizzled global src
        gA[j] = (const char*)A + (size_t)(m0 + row) * D_DIM * 2 + lc;
        gB[j] = (const char*)Bt + (size_t)(n0 + row) * D_DIM * 2 + lc;
        ldsOff[j] = o;
    }

    #define STAGE2(kt, j)                                                        \
        do {                                                                     \
            const int _b = (kt) & 3;                                             \
            gload_lds16(gA[j] + (size_t)(kt) * (GBK * 2),                        \
                        (char*)&ldsA[_b][0] + ldsOff[j]);                        \
            gload_lds16(gB[j] + (size_t)(kt) * (GBK * 2),                        \
                        (char*)&ldsB[_b][0] + ldsOff[j]);                        \
        } while (0)

    // ---- fragment read offsets (bytes within one buffer), swizzled
    int aOff0[4], aOff1[4], bOff[4];
    #pragma unroll
    for (int i = 0; i < 4; ++i) {
        int r0 = wr * 128 + i * 16 + rq;
        int r1 = r0 + 64;
        aOff0[i] = r0 * 64 + ((kq * 2) ^ (((r0 >> 1) & 3) << 4));
        aOff1[i] = r1 * 64 + ((kq * 2) ^ (((r1 >> 1) & 3) << 4));
        int rb = wc * 64 + i * 16 + rq;
        bOff[i] = rb * 64 + ((kq * 2) ^ (((rb >> 1) & 3) << 4));
    }

    f32x4 accL[4][4] = {};   // rows wr*128 + [0,64)
    f32x4 accH[4][4] = {};   // rows wr*128 + [64,128)
    bf16x8 a0[4], a1[4], bE[4], bO[4];

    // reads 8: a0 + b(next-tile) for phase0 of tile kt
    auto read_a0b = [&](int kt, bf16x8 (&bb)[4]) {
        const char* As_ = (const char*)&ldsA[kt & 3][0];
        const char* Bs_ = (const char*)&ldsB[kt & 3][0];
        #pragma unroll
        for (int i = 0; i < 4; ++i) a0[i] = *(const bf16x8*)(As_ + aOff0[i]);
        #pragma unroll
        for (int i = 0; i < 4; ++i) bb[i] = *(const bf16x8*)(Bs_ + bOff[i]);
    };
    // reads 4: a1 for phase1 of tile kt
    auto read_a1 = [&](int kt) {
        const char* As_ = (const char*)&ldsA[kt & 3][0];
        #pragma unroll
        for (int i = 0; i < 4; ++i) a1[i] = *(const bf16x8*)(As_ + aOff1[i]);
    };

    // one K-tile: bc = this tile's b frags, bn = next tile's b frag storage
    auto tile_step = [&](int kt, bf16x8 (&bc)[4], bf16x8 (&bn)[4]) {
        // ===== phase 0: pre-read a1 (this tile), stage, barrier, MFMA rows [0,64) =====
        read_a1(kt);
        if (kt + 3 < GNKT) STAGE2(kt + 3, 0);
        BARRIER();
        __builtin_amdgcn_s_setprio(1);
        #pragma unroll
        for (int mi = 0; mi < 4; ++mi)
            #pragma unroll
            for (int nj = 0; nj < 4; ++nj)
                accL[mi][nj] = __builtin_amdgcn_mfma_f32_16x16x32_bf16(a0[mi], bc[nj], accL[mi][nj], 0, 0, 0);
        __builtin_amdgcn_s_setprio(0);

        // ===== phase 1: vmcnt gate, pre-read a0+b (next tile), stage, barrier, MFMA rows [64,128) =====
        if (kt < GNKT - 3)       { asm volatile("s_waitcnt vmcnt(6)" ::: "memory"); }
        else if (kt == GNKT - 3) { asm volatile("s_waitcnt vmcnt(4)" ::: "memory"); }
        else if (kt == GNKT - 2) { asm volatile("s_waitcnt vmcnt(0)" ::: "memory"); }
        if (kt + 1 < GNKT) read_a0b(kt + 1, bn);
        if (kt + 3 < GNKT) STAGE2(kt + 3, 1);
        BARRIER();
        __builtin_amdgcn_s_setprio(1);
        #pragma unroll
        for (int mi = 0; mi < 4; ++mi)
            #pragma unroll
            for (int nj = 0; nj < 4; ++nj)
                accH[mi][nj] = __builtin_amdgcn_mfma_f32_16x16x32_bf16(a1[mi], bc[nj], accH[mi][nj], 0, 0, 0);
        __builtin_amdgcn_s_setprio(0);
    };

    // ---- prologue: stage tiles 0,1,2 (12 loads); wait tile 0 (8 newer in flight)
    #pragma unroll
    for (int t = 0; t < 3; ++t) { STAGE2(t, 0); STAGE2(t, 1); }
    asm volatile("s_waitcnt vmcnt(8)" ::: "memory");
    BARRIER();
    read_a0b(0, bE);

    for (int kt = 0; kt < GNKT; kt += 2) {
        tile_step(kt, bE, bO);
        tile_step(kt + 1, bO, bE);
    }

    // ---- epilogue: C/D layout col=lane&15, row=(lane>>4)*4+reg
    const int rr4 = (lane >> 4) * 4;
    #pragma unroll
    for (int mi = 0; mi < 4; ++mi) {
        #pragma unroll
        for (int r = 0; r < 4; ++r) {
            const int mL = m0 + wr * 128 + mi * 16 + rr4 + r;
            const float pgL = p_gen[mL];
            const int mH = mL + 64;
            const float pgH = p_gen[mH];
            #pragma unroll
            for (int nj = 0; nj < 4; ++nj) {
                const int n = n0 + wc * 64 + nj * 16 + rq;
                out[(size_t)mL * V_DIM + n] = pgL * (accL[mi][nj][r] + bias[n]);
                out[(size_t)mH * V_DIM + n] = pgH * (accH[mi][nj][r] + bias[n]);
            }
        }
    }
    #undef STAGE2
}

// ---------------- scatter: out[t,b,post[s,b]] += (1-pg[t,b]) * att[t,b,s] ----------------

__global__ void scatter_att(const float* __restrict__ att, const float* __restrict__ p_gen,
                            const int* __restrict__ post, float* __restrict__ out) {
    const int tb = blockIdx.x;             // t*B + b
    const int b = tb & (B_DIM - 1);
    const float g = 1.0f - p_gen[tb];
    float* o = out + (size_t)tb * V_DIM;
    const float* a = att + (size_t)tb * S_DIM;
    for (int s = threadIdx.x; s < S_DIM; s += blockDim.x) {
        atomicAdd(&o[post[s * B_DIM + b]], g * a[s]);
    }
}

// ---------------- fallback (ws too small): fp32 vector GEMM ----------------

#define FB_MT 16
__global__ __launch_bounds__(256)
void gemm_naive(const float* __restrict__ h, const float* __restrict__ W,
                const float* __restrict__ bias, const float* __restrict__ pg,
                float* __restrict__ out) {
    const int mb = blockIdx.y;
    const int v = blockIdx.x * 256 + threadIdx.x;
    __shared__ float hs[FB_MT][128];
    float acc[FB_MT] = {};
    for (int k0 = 0; k0 < D_DIM; k0 += 128) {
        for (int i = threadIdx.x; i < FB_MT * 128; i += 256)
            hs[i >> 7][i & 127] = h[(size_t)(mb * FB_MT + (i >> 7)) * D_DIM + k0 + (i & 127)];
        __syncthreads();
        for (int kk = 0; kk < 128; ++kk) {
            const float wv = W[(size_t)(k0 + kk) * V_DIM + v];
            #pragma unroll
            for (int i = 0; i < FB_MT; ++i) acc[i] += hs[i][kk] * wv;
        }
        __syncthreads();
    }
    #pragma unroll
    for (int i = 0; i < FB_MT; ++i) {
        const int m = mb * FB_MT + i;
        out[(size_t)m * V_DIM + v] = pg[m] * (acc[i] + bias[v]);
    }
}

// ---------------- launcher ----------------

extern "C" void kernel_launch(void* const* d_in, const int* in_sizes, int n_in,
                              void* d_out, int out_size, void* d_ws, size_t ws_size,
                              hipStream_t stream) {
    const float* h    = (const float*)d_in[0];   // (T,B,D)
    const float* W    = (const float*)d_in[1];   // (D,V)
    const float* bias = (const float*)d_in[2];   // (V,)
    const float* att  = (const float*)d_in[3];   // (T,B,S)
    const float* pg   = (const float*)d_in[4];   // (T,B,1)
    const int*   post = (const int*)d_in[5];     // (S,B)
    float* out = (float*)d_out;                  // (T,B,V) fp32

    const size_t wt_bytes = (size_t)V_DIM * D_DIM * 2;   // 98,304,000
    const size_t hb_bytes = (size_t)M_DIM * D_DIM * 2;   //  6,291,456

    if (ws_size >= wt_bytes + hb_bytes) {
        unsigned short* Wt = (unsigned short*)d_ws;
        unsigned short* hb = (unsigned short*)((char*)d_ws + wt_bytes);
        convert_h<<<1024, 256, 0, stream>>>(h, hb);
        dim3 tg(D_DIM / 64, V_DIM / 64);   // 24 x 500
        convT_W<<<tg, 256, 0, stream>>>(W, Wt);
        gemm_mfma256<<<(M_DIM / GBM) * (V_DIM / GBN), 512, 0, stream>>>(hb, Wt, bias, pg, out);
    } else {
        dim3 fg(V_DIM / 256, M_DIM / FB_MT);
        gemm_naive<<<fg, 256, 0, stream>>>(h, W, bias, pg, out);
    }

    scatter_att<<<M_DIM, 256, 0, stream>>>(att, pg, post, out);
}